// Round 6
// baseline (271.134 us; speedup 1.0000x reference)
//
#include <hip/hip_runtime.h>
#include <math.h>

// Problem: B=64, R=20, L=1024, D=2048 fp32.  out[b,l] = max_r <region[b,r,:], word[b,l,:]>
// Memory-bound: 548 MB mandatory -> ~83us @ 6.6TB/s measured-achievable.
//
// Structure:
//  - 4 waves/block, each wave owns 4 words and ALL 20 regions (words read once).
//  - regions: 2 x 20KB LDS double buffer via async global_load_lds, staged one
//    chunk ahead.
//  - words: double-buffered in REGISTERS (wvA/wvB), loaded one chunk ahead, so
//    the per-chunk FMA loop has zero VMEM waits (round-5 lesson: issuing stage
//    loads before wv loads forces vmcnt to drain the stage -> serial staging).
//  - no min-waves launch bound (rounds 3/4: VGPR caps spill the 80-reg acc).
#define BATCH 64
#define NREG  20
#define LWORDS 1024
#define DDIM  2048
#define DK    256                   // D-chunk: 20*256*4B = 20 KB per buffer
#define NCHUNK (DDIM / DK)          // 8
#define NWAVE 4
#define TPB   (NWAVE * 64)          // 256
#define WPW   4                     // words per wave
#define WORDS_PER_BLOCK (NWAVE * WPW)   // 16

// async global->LDS, 16B per lane; dst must be wave-uniform (HW adds lane*16)
__device__ __forceinline__ void gload_lds16(const float* src, float* dst) {
    __builtin_amdgcn_global_load_lds(
        (const __attribute__((address_space(1))) void*)src,
        (__attribute__((address_space(3))) void*)dst,
        16, 0, 0);
}

// DPP full-wave (64-lane) sum; result valid in lane 63.
template <int CTRL>
__device__ __forceinline__ float dpp_add_f32(float v) {
    int s = __builtin_amdgcn_update_dpp(0, __float_as_int(v), CTRL, 0xf, 0xf, true);
    return v + __int_as_float(s);
}
__device__ __forceinline__ float wave_sum64(float v) {
    v = dpp_add_f32<0x111>(v);  // row_shr:1
    v = dpp_add_f32<0x112>(v);  // row_shr:2
    v = dpp_add_f32<0x114>(v);  // row_shr:4
    v = dpp_add_f32<0x118>(v);  // row_shr:8
    v = dpp_add_f32<0x142>(v);  // row_bcast:15
    v = dpp_add_f32<0x143>(v);  // row_bcast:31 -> lane 63 = total
    return v;
}

__global__ __launch_bounds__(TPB)
void score_max_kernel(const float* __restrict__ in0,   // (B*20, D) regions
                      const float* __restrict__ in1,   // (B, L, D) words
                      float* __restrict__ out) {       // (B, 1, L)
    __shared__ float reg_lds[2][NREG * DK];            // 40 KB double buffer

    const int bid  = blockIdx.x;
    // bid = t*64 + b: batch b always lands on XCD (b%8) -> regions L2-resident.
    const int b    = bid & 63;
    const int t    = bid >> 6;
    const int tid  = threadIdx.x;
    const int wave = tid >> 6;
    const int lane = tid & 63;
    const int l0   = t * WORDS_PER_BLOCK + wave * WPW;

    const float* regbase = in0 + (size_t)b * NREG * DDIM;
    const float* wordp   = in1 + ((size_t)b * LWORDS + l0) * DDIM + lane * 4;

    // stage regions[0..19][c*DK .. +DK) into reg_lds[bufsel] (async, 5 rows/wave)
    auto stage = [&](int bufsel, int c) {
        #pragma unroll
        for (int i = 0; i < NREG / NWAVE; ++i) {        // 5 rows per wave
            const int r = i * NWAVE + wave;              // wave-uniform row
            gload_lds16(regbase + (size_t)r * DDIM + c * DK + lane * 4,
                        &reg_lds[bufsel][r * DK]);
        }
    };
    auto wvload = [&](float4* wv, int c) {
        #pragma unroll
        for (int w = 0; w < WPW; ++w)
            wv[w] = *reinterpret_cast<const float4*>(wordp + (size_t)w * DDIM + c * DK);
    };

    float acc[NREG][WPW];
    #pragma unroll
    for (int r = 0; r < NREG; ++r)
        #pragma unroll
        for (int w = 0; w < WPW; ++w) acc[r][w] = 0.0f;

    auto compute = [&](int bufsel, const float4* wv) {
        const float* rbase = &reg_lds[bufsel][lane * 4];
        #pragma unroll
        for (int r = 0; r < NREG; ++r) {
            const float4 rv = *reinterpret_cast<const float4*>(rbase + r * DK);
            #pragma unroll
            for (int w = 0; w < WPW; ++w) {
                float a = acc[r][w];
                a = fmaf(rv.x, wv[w].x, a);
                a = fmaf(rv.y, wv[w].y, a);
                a = fmaf(rv.z, wv[w].z, a);
                a = fmaf(rv.w, wv[w].w, a);
                acc[r][w] = a;
            }
        }
    };

    float4 wvA[WPW], wvB[WPW];

    // prologue: chunk 0 stage + words (drained by the first barrier)
    stage(0, 0);
    wvload(wvA, 0);

    // 2-chunk unrolled main loop: static ping-pong of {lds buffer, wv regs}.
    #pragma unroll
    for (int cc = 0; cc < NCHUNK; cc += 2) {
        __syncthreads();                 // drains stage(cc)+wvA(cc); lds[1] readers done
        if (cc + 1 < NCHUNK) { stage(1, cc + 1); wvload(wvB, cc + 1); }
        compute(0, wvA);                 // no VMEM waits: wvA already complete

        __syncthreads();                 // drains stage(cc+1)+wvB; lds[0] readers done
        if (cc + 2 < NCHUNK) { stage(0, cc + 2); wvload(wvA, cc + 2); }
        compute(1, wvB);
    }

    // epilogue: DPP wave-sum each acc, max over regions, lane 63 stores.
    #pragma unroll
    for (int w = 0; w < WPW; ++w) {
        float m = -INFINITY;
        #pragma unroll
        for (int r = 0; r < NREG; ++r)
            m = fmaxf(m, wave_sum64(acc[r][w]));
        if (lane == 63) out[(size_t)b * LWORDS + l0 + w] = m;
    }
}

extern "C" void kernel_launch(void* const* d_in, const int* in_sizes, int n_in,
                              void* d_out, int out_size, void* d_ws, size_t ws_size,
                              hipStream_t stream) {
    const float* in0 = (const float*)d_in[0];   // (B*20, D)
    const float* in1 = (const float*)d_in[1];   // (B, L, D)
    float* out = (float*)d_out;                  // (B, 1, L)

    const int grid = BATCH * (LWORDS / WORDS_PER_BLOCK);   // 64 * 64 = 4096
    score_max_kernel<<<grid, TPB, 0, stream>>>(in0, in1, out);
}